// Round 13
// baseline (96.018 us; speedup 1.0000x reference)
//
#include <hip/hip_runtime.h>
#include <cstdint>

#define NXC 768
#define NHEAD 12
#define BB 2
#define SS 2048
#define MTOT (BB*SS)        // 4096
#define NQKV (3*NXC)        // 2304
#define PRESENT_HALF (BB*NHEAD*SS*64)   // 3145728

typedef __bf16 bf16x8 __attribute__((ext_vector_type(8)));
typedef float f32x4 __attribute__((ext_vector_type(4)));
typedef float f32x16 __attribute__((ext_vector_type(16)));

__device__ __forceinline__ uint16_t f2bf(float f) {
    uint32_t u = __builtin_bit_cast(uint32_t, f);
    uint32_t r = (u + 0x7FFFu + ((u >> 16) & 1u)) >> 16;
    return (uint16_t)r;
}

__device__ __forceinline__ bf16x8 vfrag(ushort4 a, ushort4 b) {
    union { bf16x8 v; ushort4 u[2]; } r;
    r.u[0] = a; r.u[1] = b;
    return r.v;
}

// async global->LDS, 16B per lane; lds dest = wave-uniform base + lane*16
__device__ __forceinline__ void gload16(const uint16_t* g, uint16_t* l) {
    __builtin_amdgcn_global_load_lds(
        (const __attribute__((address_space(1))) unsigned int*)g,
        (__attribute__((address_space(3))) unsigned int*)l, 16, 0, 0);
}

// ---------------- merged prep kernel ----------------
// blocks [0,3072): x->bf16 ; [3072,3504): weffT tiles ; [3504,3648): wpT tiles

__global__ __launch_bounds__(256) void prep_all(
    const float* __restrict__ x, uint16_t* __restrict__ x_bf,
    const float* __restrict__ w_attn, const float* __restrict__ lora_A,
    const float* __restrict__ lora_B, uint16_t* __restrict__ weffT,
    const float* __restrict__ w_proj, uint16_t* __restrict__ wpT) {
    __shared__ float T[64][65];
    __shared__ float Af[8][64];
    __shared__ float Bf[64][8];
    const int t = threadIdx.x;
    const int blk = blockIdx.x;
    if (blk < 3072) {
        int i = blk * 256 + t;
        float4 v = ((const float4*)x)[i];
        ushort4 o;
        o.x = f2bf(v.x); o.y = f2bf(v.y); o.z = f2bf(v.z); o.w = f2bf(v.w);
        ((ushort4*)x_bf)[i] = o;
        return;
    }
    if (blk < 3504) {
        const int i2 = blk - 3072;
        const int n0 = (i2 % 36) * 64, k0 = (i2 / 36) * 64;
        const int c = n0 / NXC;
        {
            const int nn = t & 63, q = t >> 6;
#pragma unroll
            for (int j = 0; j < 16; ++j) {
                int kr = q + j * 4;
                T[kr][nn] = w_attn[(size_t)(k0 + kr) * NQKV + n0 + nn];
            }
        }
        {
            int idx = t;
            Af[idx >> 6][idx & 63] = lora_A[(size_t)(c * 8 + (idx >> 6)) * NXC + k0 + (idx & 63)];
            idx += 256;
            Af[idx >> 6][idx & 63] = lora_A[(size_t)(c * 8 + (idx >> 6)) * NXC + k0 + (idx & 63)];
            Bf[t >> 3][t & 7] = lora_B[(size_t)(n0 + (t >> 3)) * 8 + (t & 7)];
            idx = t + 256;
            Bf[idx >> 3][idx & 7] = lora_B[(size_t)(n0 + (idx >> 3)) * 8 + (idx & 7)];
        }
        __syncthreads();
        const int kk = t & 63, q = t >> 6;
#pragma unroll
        for (int j = 0; j < 16; ++j) {
            int nn = q + j * 4;
            float d = 0.f;
#pragma unroll
            for (int r = 0; r < 8; ++r) d += Af[r][kk] * Bf[nn][r];
            weffT[(size_t)(n0 + nn) * NXC + k0 + kk] = f2bf(T[kk][nn] + 16.0f * d);
        }
        return;
    }
    {
        const int i3 = blk - 3504;
        const int n0 = (i3 % 12) * 64, k0 = (i3 / 12) * 64;
        {
            const int nn = t & 63, q = t >> 6;
#pragma unroll
            for (int j = 0; j < 16; ++j) {
                int kr = q + j * 4;
                T[kr][nn] = w_proj[(size_t)(k0 + kr) * NXC + n0 + nn];
            }
        }
        __syncthreads();
        const int kk = t & 63, q = t >> 6;
#pragma unroll
        for (int j = 0; j < 16; ++j) {
            int nn = q + j * 4;
            wpT[(size_t)(n0 + nn) * NXC + k0 + kk] = f2bf(T[kk][nn]);
        }
    }
}

// ---------------- GEMM: C = A[M,768]*BT[N,768]^T ----------------
// BK=64, 3-buffer, stage 2 ahead, counted vmcnt(6) (T3/T4). XOR-swizzled LDS
// (rule #21: pre-swizzled global src, linear dest). 6 loads/wave/stage.

template<int MODE, int BM, int BN, int NBX>
__global__ __launch_bounds__(256) void gemm_bt(
    const uint16_t* __restrict__ Abf, const uint16_t* __restrict__ BTbf,
    const float* __restrict__ bias, float* __restrict__ outf,
    uint16_t* __restrict__ q_bf, uint16_t* __restrict__ k_bf,
    uint16_t* __restrict__ vT_bf) {
    constexpr int MR = BM / 32;
    constexpr int NR = BN / 32;
    constexpr int AI = BM / 32;
    constexpr int BI = BN / 32;
    __shared__ uint16_t As[3][BM][64];
    __shared__ uint16_t Bs[3][BN][64];
    const int t = threadIdx.x;
    const int lane = t & 63;
    const int w = t >> 6;
    const int wr = (w >> 1) * (BM / 2);
    const int wc = (w & 1) * (BN / 2);
    const int lr16 = lane & 15;
    const int hi2 = lane >> 4;
    const int id = blockIdx.x;
    const int wgid = (id & 7) * ((int)gridDim.x >> 3) + (id >> 3);
    const int by = wgid / NBX, bx = wgid - by * NBX;
    const size_t arow0 = (size_t)by * BM;
    const size_t brow0 = (size_t)bx * BN;
    const int srow = lane >> 3;
    const int schunk = ((lane & 7) ^ (srow & 7)) << 3;
    const uint16_t* Asrc = Abf + (arow0 + w * (BM / 4) + srow) * NXC + schunk;
    const uint16_t* Bsrc = BTbf + (brow0 + w * (BN / 4) + srow) * NXC + schunk;

    f32x4 acc[MR][NR];
#pragma unroll
    for (int m = 0; m < MR; ++m)
#pragma unroll
        for (int n = 0; n < NR; ++n) acc[m][n] = (f32x4){0.f, 0.f, 0.f, 0.f};

#define STAGE(buf, k0) do { \
    _Pragma("unroll") \
    for (int j = 0; j < AI; ++j) \
        gload16(Asrc + (size_t)(j * 8) * NXC + (k0), &As[buf][w * (BM / 4) + j * 8][0]); \
    _Pragma("unroll") \
    for (int j = 0; j < BI; ++j) \
        gload16(Bsrc + (size_t)(j * 8) * NXC + (k0), &Bs[buf][w * (BN / 4) + j * 8][0]); \
} while (0)

    STAGE(0, 0);
    STAGE(1, 64);

    int cur = 0;                      // buffer = kt % 3
    for (int kt = 0; kt < 12; ++kt) {
        if (kt + 1 < 12) asm volatile("s_waitcnt vmcnt(6)" ::: "memory");  // stage(kt) done
        else             asm volatile("s_waitcnt vmcnt(0)" ::: "memory");
        __builtin_amdgcn_s_barrier();
        __builtin_amdgcn_sched_barrier(0);
        if (kt + 2 < 12) {
            int b2 = cur + 2; if (b2 >= 3) b2 -= 3;
            STAGE(b2, (kt + 2) << 6);
        }
        bf16x8 af[2][MR], bv[2][NR];
#pragma unroll
        for (int kk = 0; kk < 2; ++kk) {
#pragma unroll
            for (int m = 0; m < MR; ++m) {
                const int r = wr + m * 16 + lr16;
                af[kk][m] = *(const bf16x8*)&As[cur][r][(((kk * 4 + hi2) ^ (r & 7)) << 3)];
            }
#pragma unroll
            for (int n = 0; n < NR; ++n) {
                const int r = wc + n * 16 + lr16;
                bv[kk][n] = *(const bf16x8*)&Bs[cur][r][(((kk * 4 + hi2) ^ (r & 7)) << 3)];
            }
        }
        __builtin_amdgcn_s_setprio(1);
#pragma unroll
        for (int kk = 0; kk < 2; ++kk)
#pragma unroll
            for (int m = 0; m < MR; ++m)
#pragma unroll
                for (int n = 0; n < NR; ++n)
                    acc[m][n] = __builtin_amdgcn_mfma_f32_16x16x32_bf16(af[kk][m], bv[kk][n],
                                                                        acc[m][n], 0, 0, 0);
        __builtin_amdgcn_s_setprio(0);
        cur = (cur == 2) ? 0 : cur + 1;
    }
#undef STAGE

    const int rowb = (lane >> 4) << 2;
    const float QSCALE = 0.125f * 1.44269504f;
#pragma unroll
    for (int m = 0; m < MR; ++m) {
        int grow0 = (int)arow0 + wr + m * 16 + rowb;
#pragma unroll
        for (int n = 0; n < NR; ++n) {
            int gcol = (int)brow0 + wc + n * 16 + lr16;
            float bvs = bias[gcol];
            if (MODE == 1) {
#pragma unroll
                for (int ri = 0; ri < 4; ++ri) {
                    int grow = grow0 + ri;
                    outf[(size_t)grow * NXC + gcol] = acc[m][n][ri] + bvs;
                }
            } else {
                int c = gcol >= 2 * NXC ? 2 : (gcol >= NXC ? 1 : 0);
                int e = gcol - c * NXC;
                int h = e >> 6, d = e & 63;
                int b = grow0 >> 11, s0 = grow0 & 2047;
                if (c == 0) {
#pragma unroll
                    for (int ri = 0; ri < 4; ++ri) {
                        float v = acc[m][n][ri] + bvs;
                        q_bf[((size_t)(b * NHEAD + h) * SS + s0 + ri) * 64 + d] = f2bf(v * QSCALE);
                    }
                } else if (c == 1) {
#pragma unroll
                    for (int ri = 0; ri < 4; ++ri) {
                        float v = acc[m][n][ri] + bvs;
                        size_t hidx = (size_t)(b * NHEAD + h) * SS + s0 + ri;
                        k_bf[hidx * 64 + d] = f2bf(v);
                        outf[hidx * 64 + d] = v;
                    }
                } else {
                    float v0 = acc[m][n][0] + bvs, v1 = acc[m][n][1] + bvs;
                    float v2 = acc[m][n][2] + bvs, v3 = acc[m][n][3] + bvs;
                    ushort4 pv;
                    pv.x = f2bf(v0); pv.y = f2bf(v1); pv.z = f2bf(v2); pv.w = f2bf(v3);
                    *(ushort4*)(vT_bf + ((size_t)(b * NHEAD + h) * 64 + d) * SS + s0) = pv;
                    size_t hb = ((size_t)(b * NHEAD + h) * SS + s0) * 64 + d;
                    outf[PRESENT_HALF + hb] = v0;
                    outf[PRESENT_HALF + hb + 64] = v1;
                    outf[PRESENT_HALF + hb + 128] = v2;
                    outf[PRESENT_HALF + hb + 192] = v3;
                }
            }
        }
    }
}

// ---------------- flash attention: 64-row q-block, 4 waves = (q-half x key-half) ----
// (unchanged from round 11: 3-buffer, stage 2 ahead, counted vmcnt(4))

__global__ __launch_bounds__(256) void attn_kernel(
    const uint16_t* __restrict__ qb, const uint16_t* __restrict__ kb,
    const uint16_t* __restrict__ vtb, uint16_t* __restrict__ ab) {
    __shared__ __align__(16) uint8_t smem[49152];   // KT[3][64][64] | VT[3][64][64]
    uint16_t* KT0 = (uint16_t*)smem;                 // + buf*4096 elems
    uint16_t* VT0 = (uint16_t*)(smem + 24576);
    float* Mlp = (float*)smem;                       // epilogue overlay (K/V dead)
    float* Llp = Mlp + 64;
    float* Ofp = Llp + 64;                           // Of[64][68] f32

    const int t = threadIdx.x;
    const int w = t >> 6, lane = t & 63;
    const int qw = w & 1, khalf = w >> 1;
    const int l31 = lane & 31, hi = lane >> 5;
    const int i8 = lane >> 3, c8 = lane & 7;
    const int id = blockIdx.x;
    const int xcd = id & 7, slot = id >> 3;
    const int lh = slot % 3, qs = slot / 3;
    const int qi = 31 - qs;                    // heavy q-blocks dispatch first
    const int bh = xcd * 3 + lh;
    const int qbase = qi * 64;
    const int q = qbase + qw * 32 + l31;
    const uint16_t* qh = qb + (size_t)bh * (SS * 64);
    const uint16_t* kh = kb + (size_t)bh * (SS * 64);
    const uint16_t* vh = vtb + (size_t)bh * (64 * SS);
    const int nkt = qi + 1;

    bf16x8 qf[4];
#pragma unroll
    for (int dc = 0; dc < 4; ++dc)
        qf[dc] = *(const bf16x8*)(qh + (size_t)q * 64 + dc * 16 + hi * 8);

    f32x16 o0, o1;
#pragma unroll
    for (int i = 0; i < 16; ++i) { o0[i] = 0.f; o1[i] = 0.f; }
    float m_run = -1e30f, l_run = 0.f;

    const uint16_t* ksrc = kh + (size_t)i8 * 64 + ((c8 ^ i8) << 3);
    const uint16_t* vsrc = vh + (size_t)i8 * SS + ((c8 ^ i8) << 3);
    const int j0 = (w & 1) * 4;

#define ASTAGE(buf, nb) do { \
    if (khalf == 0) { \
        uint16_t* KTn = KT0 + (buf) * 4096; \
        _Pragma("unroll") \
        for (int j = 0; j < 4; ++j) \
            gload16(ksrc + (size_t)((nb) + (j0 + j) * 8) * 64, KTn + (j0 + j) * 8 * 64); \
    } else { \
        uint16_t* VTn = VT0 + (buf) * 4096; \
        _Pragma("unroll") \
        for (int j = 0; j < 4; ++j) \
            gload16(vsrc + (size_t)((j0 + j) * 8) * SS + (nb), VTn + (j0 + j) * 8 * 64); \
    } \
} while (0)

    ASTAGE(0, 0);
    if (nkt > 1) ASTAGE(1, 64);

    int cur = 0;                     // buffer index = kt % 3
    for (int kt = 0; kt < nkt; ++kt) {
        if (kt + 1 < nkt) asm volatile("s_waitcnt vmcnt(4)" ::: "memory");
        else              asm volatile("s_waitcnt vmcnt(0)" ::: "memory");
        __builtin_amdgcn_s_barrier();
        __builtin_amdgcn_sched_barrier(0);
        if (kt + 2 < nkt) {
            int b2 = cur + 2; if (b2 >= 3) b2 -= 3;
            ASTAGE(b2, (kt + 2) << 6);
        }
        const uint16_t* KTc = KT0 + cur * 4096;
        const uint16_t* VTc = VT0 + cur * 4096;

        f32x16 sa;
#pragma unroll
        for (int i = 0; i < 16; ++i) sa[i] = 0.f;
        const int krow = khalf * 32 + l31;
        __builtin_amdgcn_s_setprio(1);
#pragma unroll
        for (int dc = 0; dc < 4; ++dc) {
            bf16x8 kf = *(const bf16x8*)(KTc + krow * 64 + (((dc * 2 + hi) ^ (l31 & 7)) << 3));
            sa = __builtin_amdgcn_mfma_f32_32x32x16_bf16(kf, qf[dc], sa, 0, 0, 0);
        }
        __builtin_amdgcn_s_setprio(0);
        if (kt == qi) {
            const int qrel = qw * 32 + l31;
#pragma unroll
            for (int r = 0; r < 16; ++r) {
                int key = khalf * 32 + (r & 3) + 8 * (r >> 2) + 4 * hi;
                sa[r] = (key > qrel) ? -1e30f : sa[r];
            }
        }
        float m8[8];
#pragma unroll
        for (int g = 0; g < 8; ++g) m8[g] = fmaxf(sa[g * 2], sa[g * 2 + 1]);
        float lm = fmaxf(fmaxf(fmaxf(m8[0], m8[1]), fmaxf(m8[2], m8[3])),
                         fmaxf(fmaxf(m8[4], m8[5]), fmaxf(m8[6], m8[7])));
        if (__any(lm > m_run + 8.f)) {
            float tmf = fmaxf(lm, __shfl_xor(lm, 32));
            float nm = fmaxf(m_run, tmf);
            float corr = __builtin_amdgcn_exp2f(m_run - nm);
            l_run *= corr;
#pragma unroll
            for (int i = 0; i < 16; ++i) { o0[i] *= corr; o1[i] *= corr; }
            m_run = nm;
        }
        float e[16];
#pragma unroll
        for (int r = 0; r < 16; ++r) e[r] = __builtin_amdgcn_exp2f(sa[r] - m_run);
        bf16x8 pa0, pa1;
#pragma unroll
        for (int r = 0; r < 8; ++r) { pa0[r] = (__bf16)e[r]; pa1[r] = (__bf16)e[8 + r]; }
        l_run += ((e[0] + e[1]) + (e[2] + e[3])) + ((e[4] + e[5]) + (e[6] + e[7]))
               + ((e[8] + e[9]) + (e[10] + e[11])) + ((e[12] + e[13]) + (e[14] + e[15]));
        const int rx = l31 & 7;
        __builtin_amdgcn_s_setprio(1);
#pragma unroll
        for (int dblk = 0; dblk < 2; ++dblk) {
            const uint16_t* vrow = VTc + (dblk * 32 + l31) * 64;
            ushort4 v0 = *(const ushort4*)(vrow + (((khalf * 4 + 0) ^ rx) << 3) + hi * 4);
            ushort4 v1 = *(const ushort4*)(vrow + (((khalf * 4 + 1) ^ rx) << 3) + hi * 4);
            ushort4 v2 = *(const ushort4*)(vrow + (((khalf * 4 + 2) ^ rx) << 3) + hi * 4);
            ushort4 v3 = *(const ushort4*)(vrow + (((khalf * 4 + 3) ^ rx) << 3) + hi * 4);
            f32x16 oo = dblk ? o1 : o0;
            oo = __builtin_amdgcn_mfma_f32_32x32x16_bf16(vfrag(v0, v1), pa0, oo, 0, 0, 0);
            oo = __builtin_amdgcn_mfma_f32_32x32x16_bf16(vfrag(v2, v3), pa1, oo, 0, 0, 0);
            if (dblk) o1 = oo; else o0 = oo;
        }
        __builtin_amdgcn_s_setprio(0);
        cur = (cur == 2) ? 0 : cur + 1;
    }
#undef ASTAGE

    __syncthreads();   // all waves done reading K/V LDS before overlay writes

    const float lf = l_run + __shfl_xor(l_run, 32);
    const int qrow = qw * 32 + l31;
    if (khalf == 1) {
        if (hi == 0) { Mlp[qrow] = m_run; Llp[qrow] = lf; }
#pragma unroll
        for (int dblk = 0; dblk < 2; ++dblk)
#pragma unroll
            for (int rg = 0; rg < 4; ++rg) {
                f32x16 oo = dblk ? o1 : o0;
                f32x4 v;
                v[0] = oo[rg * 4 + 0]; v[1] = oo[rg * 4 + 1];
                v[2] = oo[rg * 4 + 2]; v[3] = oo[rg * 4 + 3];
                *(f32x4*)&Ofp[qrow * 68 + dblk * 32 + rg * 8 + hi * 4] = v;
            }
    }
    __syncthreads();
    if (khalf == 0) {
        const float m2 = Mlp[qrow], l2 = Llp[qrow];
        const float ms = fmaxf(m_run, m2);
        const float wA = __builtin_amdgcn_exp2f(m_run - ms);
        const float wB = __builtin_amdgcn_exp2f(m2 - ms);
        const float inv = 1.f / (lf * wA + l2 * wB);
        const int b = bh / NHEAD, h = bh - b * NHEAD;
        uint16_t* abp = ab + ((size_t)(b * SS + q)) * NXC + h * 64;
#pragma unroll
        for (int dblk = 0; dblk < 2; ++dblk)
#pragma unroll
            for (int rg = 0; rg < 4; ++rg) {
                f32x16 oo = dblk ? o1 : o0;
                f32x4 po = *(const f32x4*)&Ofp[qrow * 68 + dblk * 32 + rg * 8 + hi * 4];
                ushort4 wv;
                wv.x = f2bf((oo[rg * 4 + 0] * wA + po[0] * wB) * inv);
                wv.y = f2bf((oo[rg * 4 + 1] * wA + po[1] * wB) * inv);
                wv.z = f2bf((oo[rg * 4 + 2] * wA + po[2] * wB) * inv);
                wv.w = f2bf((oo[rg * 4 + 3] * wA + po[3] * wB) * inv);
                *(ushort4*)(abp + dblk * 32 + rg * 8 + hi * 4) = wv;
            }
    }
}

// ---------------- launch ----------------

extern "C" void kernel_launch(void* const* d_in, const int* in_sizes, int n_in,
                              void* d_out, int out_size, void* d_ws, size_t ws_size,
                              hipStream_t stream) {
    const float* x      = (const float*)d_in[0];
    const float* w_attn = (const float*)d_in[1];
    const float* b_attn = (const float*)d_in[2];
    const float* lora_A = (const float*)d_in[3];
    const float* lora_B = (const float*)d_in[4];
    const float* w_proj = (const float*)d_in[5];
    const float* b_proj = (const float*)d_in[6];
    float* out = (float*)d_out;
    float* present = out + (size_t)MTOT * NXC;   // 3145728

    uint16_t* ws    = (uint16_t*)d_ws;
    uint16_t* x_bf  = ws;                         // 3145728
    uint16_t* weffT = x_bf + 3145728;             // 1769472
    uint16_t* wpT   = weffT + 1769472;            // 589824
    uint16_t* q_bf  = wpT + 589824;               // 3145728
    uint16_t* k_bf  = q_bf + 3145728;             // 3145728
    uint16_t* vT_bf = k_bf + 3145728;             // 3145728
    uint16_t* a_bf  = vT_bf + 3145728;            // 3145728

    prep_all<<<dim3(3648), dim3(256), 0, stream>>>(x, x_bf, w_attn, lora_A, lora_B,
                                                   weffT, w_proj, wpT);
    // gemm0: 4096x2304, 128x64 tile -> 1152 blocks (XCD-swizzled)
    gemm_bt<0, 128, 64, 36><<<dim3(1152), dim3(256), 0, stream>>>(
        x_bf, weffT, b_attn, present, q_bf, k_bf, vT_bf);
    attn_kernel<<<dim3(768), dim3(256), 0, stream>>>(q_bf, k_bf, vT_bf, a_bf);
    // gemm1: 4096x768, 128x64 tile -> 384 blocks
    gemm_bt<1, 128, 64, 12><<<dim3(384), dim3(256), 0, stream>>>(
        a_bf, wpT, b_proj, out, nullptr, nullptr, nullptr);
}

// Round 14
// 87.190 us; speedup vs baseline: 1.1012x; 1.1012x over previous
//
#include <hip/hip_runtime.h>
#include <cstdint>

#define NXC 768
#define NHEAD 12
#define BB 2
#define SS 2048
#define MTOT (BB*SS)        // 4096
#define NQKV (3*NXC)        // 2304
#define PRESENT_HALF (BB*NHEAD*SS*64)   // 3145728

typedef __bf16 bf16x8 __attribute__((ext_vector_type(8)));
typedef float f32x4 __attribute__((ext_vector_type(4)));
typedef float f32x16 __attribute__((ext_vector_type(16)));

__device__ __forceinline__ uint16_t f2bf(float f) {
    uint32_t u = __builtin_bit_cast(uint32_t, f);
    uint32_t r = (u + 0x7FFFu + ((u >> 16) & 1u)) >> 16;
    return (uint16_t)r;
}

__device__ __forceinline__ bf16x8 vfrag(ushort4 a, ushort4 b) {
    union { bf16x8 v; ushort4 u[2]; } r;
    r.u[0] = a; r.u[1] = b;
    return r.v;
}

// async global->LDS, 16B per lane; lds dest = wave-uniform base + lane*16
__device__ __forceinline__ void gload16(const uint16_t* g, uint16_t* l) {
    __builtin_amdgcn_global_load_lds(
        (const __attribute__((address_space(1))) unsigned int*)g,
        (__attribute__((address_space(3))) unsigned int*)l, 16, 0, 0);
}

// ---------------- merged prep kernel ----------------
// blocks [0,3072): x->bf16 ; [3072,3504): weffT tiles ; [3504,3648): wpT tiles

__global__ __launch_bounds__(256) void prep_all(
    const float* __restrict__ x, uint16_t* __restrict__ x_bf,
    const float* __restrict__ w_attn, const float* __restrict__ lora_A,
    const float* __restrict__ lora_B, uint16_t* __restrict__ weffT,
    const float* __restrict__ w_proj, uint16_t* __restrict__ wpT) {
    __shared__ float T[64][65];
    __shared__ float Af[8][64];
    __shared__ float Bf[64][8];
    const int t = threadIdx.x;
    const int blk = blockIdx.x;
    if (blk < 3072) {
        int i = blk * 256 + t;
        float4 v = ((const float4*)x)[i];
        ushort4 o;
        o.x = f2bf(v.x); o.y = f2bf(v.y); o.z = f2bf(v.z); o.w = f2bf(v.w);
        ((ushort4*)x_bf)[i] = o;
        return;
    }
    if (blk < 3504) {
        const int i2 = blk - 3072;
        const int n0 = (i2 % 36) * 64, k0 = (i2 / 36) * 64;
        const int c = n0 / NXC;
        {
            const int nn = t & 63, q = t >> 6;
#pragma unroll
            for (int j = 0; j < 16; ++j) {
                int kr = q + j * 4;
                T[kr][nn] = w_attn[(size_t)(k0 + kr) * NQKV + n0 + nn];
            }
        }
        {
            int idx = t;
            Af[idx >> 6][idx & 63] = lora_A[(size_t)(c * 8 + (idx >> 6)) * NXC + k0 + (idx & 63)];
            idx += 256;
            Af[idx >> 6][idx & 63] = lora_A[(size_t)(c * 8 + (idx >> 6)) * NXC + k0 + (idx & 63)];
            Bf[t >> 3][t & 7] = lora_B[(size_t)(n0 + (t >> 3)) * 8 + (t & 7)];
            idx = t + 256;
            Bf[idx >> 3][idx & 7] = lora_B[(size_t)(n0 + (idx >> 3)) * 8 + (idx & 7)];
        }
        __syncthreads();
        const int kk = t & 63, q = t >> 6;
#pragma unroll
        for (int j = 0; j < 16; ++j) {
            int nn = q + j * 4;
            float d = 0.f;
#pragma unroll
            for (int r = 0; r < 8; ++r) d += Af[r][kk] * Bf[nn][r];
            weffT[(size_t)(n0 + nn) * NXC + k0 + kk] = f2bf(T[kk][nn] + 16.0f * d);
        }
        return;
    }
    {
        const int i3 = blk - 3504;
        const int n0 = (i3 % 12) * 64, k0 = (i3 / 12) * 64;
        {
            const int nn = t & 63, q = t >> 6;
#pragma unroll
            for (int j = 0; j < 16; ++j) {
                int kr = q + j * 4;
                T[kr][nn] = w_proj[(size_t)(k0 + kr) * NXC + n0 + nn];
            }
        }
        __syncthreads();
        const int kk = t & 63, q = t >> 6;
#pragma unroll
        for (int j = 0; j < 16; ++j) {
            int nn = q + j * 4;
            wpT[(size_t)(n0 + nn) * NXC + k0 + kk] = f2bf(T[kk][nn]);
        }
    }
}

// ---------------- GEMM: C = A[M,768]*BT[N,768]^T ----------------
// BK=64, 2-buf (stage t+1 -> compute t -> vmcnt(0)+barrier), XOR-swizzled LDS
// (rule #21: pre-swizzled global src, linear dest). Proven r10/r11 config.

template<int MODE, int BM, int BN, int NBX>
__global__ __launch_bounds__(256) void gemm_bt(
    const uint16_t* __restrict__ Abf, const uint16_t* __restrict__ BTbf,
    const float* __restrict__ bias, float* __restrict__ outf,
    uint16_t* __restrict__ q_bf, uint16_t* __restrict__ k_bf,
    uint16_t* __restrict__ vT_bf) {
    constexpr int MR = BM / 32;
    constexpr int NR = BN / 32;
    constexpr int AI = BM / 32;
    constexpr int BI = BN / 32;
    __shared__ uint16_t As[2][BM][64];
    __shared__ uint16_t Bs[2][BN][64];
    const int t = threadIdx.x;
    const int lane = t & 63;
    const int w = t >> 6;
    const int wr = (w >> 1) * (BM / 2);
    const int wc = (w & 1) * (BN / 2);
    const int lr16 = lane & 15;
    const int hi2 = lane >> 4;
    const int id = blockIdx.x;
    const int wgid = (id & 7) * ((int)gridDim.x >> 3) + (id >> 3);
    const int by = wgid / NBX, bx = wgid - by * NBX;
    const size_t arow0 = (size_t)by * BM;
    const size_t brow0 = (size_t)bx * BN;
    const int srow = lane >> 3;
    const int schunk = ((lane & 7) ^ (srow & 7)) << 3;
    const uint16_t* Asrc = Abf + (arow0 + w * (BM / 4) + srow) * NXC + schunk;
    const uint16_t* Bsrc = BTbf + (brow0 + w * (BN / 4) + srow) * NXC + schunk;

    f32x4 acc[MR][NR];
#pragma unroll
    for (int m = 0; m < MR; ++m)
#pragma unroll
        for (int n = 0; n < NR; ++n) acc[m][n] = (f32x4){0.f, 0.f, 0.f, 0.f};

#define STAGE(buf, k0) do { \
    _Pragma("unroll") \
    for (int j = 0; j < AI; ++j) \
        gload16(Asrc + (size_t)(j * 8) * NXC + (k0), &As[buf][w * (BM / 4) + j * 8][0]); \
    _Pragma("unroll") \
    for (int j = 0; j < BI; ++j) \
        gload16(Bsrc + (size_t)(j * 8) * NXC + (k0), &Bs[buf][w * (BN / 4) + j * 8][0]); \
} while (0)

    STAGE(0, 0);
    asm volatile("s_waitcnt vmcnt(0)" ::: "memory");
    __builtin_amdgcn_s_barrier();

    int cur = 0;
    for (int kt = 0; kt < 12; ++kt) {
        if (kt + 1 < 12) STAGE(cur ^ 1, (kt + 1) << 6);
        bf16x8 af[2][MR], bv[2][NR];
#pragma unroll
        for (int kk = 0; kk < 2; ++kk) {
#pragma unroll
            for (int m = 0; m < MR; ++m) {
                const int r = wr + m * 16 + lr16;
                af[kk][m] = *(const bf16x8*)&As[cur][r][(((kk * 4 + hi2) ^ (r & 7)) << 3)];
            }
#pragma unroll
            for (int n = 0; n < NR; ++n) {
                const int r = wc + n * 16 + lr16;
                bv[kk][n] = *(const bf16x8*)&Bs[cur][r][(((kk * 4 + hi2) ^ (r & 7)) << 3)];
            }
        }
        __builtin_amdgcn_s_setprio(1);
#pragma unroll
        for (int kk = 0; kk < 2; ++kk)
#pragma unroll
            for (int m = 0; m < MR; ++m)
#pragma unroll
                for (int n = 0; n < NR; ++n)
                    acc[m][n] = __builtin_amdgcn_mfma_f32_16x16x32_bf16(af[kk][m], bv[kk][n],
                                                                        acc[m][n], 0, 0, 0);
        __builtin_amdgcn_s_setprio(0);
        asm volatile("s_waitcnt vmcnt(0)" ::: "memory");
        __builtin_amdgcn_s_barrier();
        cur ^= 1;
    }
#undef STAGE

    const int rowb = (lane >> 4) << 2;
    const float QSCALE = 0.125f * 1.44269504f;
#pragma unroll
    for (int m = 0; m < MR; ++m) {
        int grow0 = (int)arow0 + wr + m * 16 + rowb;
#pragma unroll
        for (int n = 0; n < NR; ++n) {
            int gcol = (int)brow0 + wc + n * 16 + lr16;
            float bvs = bias[gcol];
            if (MODE == 1) {
#pragma unroll
                for (int ri = 0; ri < 4; ++ri) {
                    int grow = grow0 + ri;
                    outf[(size_t)grow * NXC + gcol] = acc[m][n][ri] + bvs;
                }
            } else {
                int c = gcol >= 2 * NXC ? 2 : (gcol >= NXC ? 1 : 0);
                int e = gcol - c * NXC;
                int h = e >> 6, d = e & 63;
                int b = grow0 >> 11, s0 = grow0 & 2047;
                if (c == 0) {
#pragma unroll
                    for (int ri = 0; ri < 4; ++ri) {
                        float v = acc[m][n][ri] + bvs;
                        q_bf[((size_t)(b * NHEAD + h) * SS + s0 + ri) * 64 + d] = f2bf(v * QSCALE);
                    }
                } else if (c == 1) {
#pragma unroll
                    for (int ri = 0; ri < 4; ++ri) {
                        float v = acc[m][n][ri] + bvs;
                        size_t hidx = (size_t)(b * NHEAD + h) * SS + s0 + ri;
                        k_bf[hidx * 64 + d] = f2bf(v);
                        outf[hidx * 64 + d] = v;
                    }
                } else {
                    float v0 = acc[m][n][0] + bvs, v1 = acc[m][n][1] + bvs;
                    float v2 = acc[m][n][2] + bvs, v3 = acc[m][n][3] + bvs;
                    ushort4 pv;
                    pv.x = f2bf(v0); pv.y = f2bf(v1); pv.z = f2bf(v2); pv.w = f2bf(v3);
                    *(ushort4*)(vT_bf + ((size_t)(b * NHEAD + h) * 64 + d) * SS + s0) = pv;
                    size_t hb = ((size_t)(b * NHEAD + h) * SS + s0) * 64 + d;
                    outf[PRESENT_HALF + hb] = v0;
                    outf[PRESENT_HALF + hb + 64] = v1;
                    outf[PRESENT_HALF + hb + 128] = v2;
                    outf[PRESENT_HALF + hb + 192] = v3;
                }
            }
        }
    }
}

// ---------------- flash attention: 64-row q-block, 4 waves = (q-half x key-half) ----
// (r11 proven: 3-buffer, stage 2 ahead, counted vmcnt(4))

__global__ __launch_bounds__(256) void attn_kernel(
    const uint16_t* __restrict__ qb, const uint16_t* __restrict__ kb,
    const uint16_t* __restrict__ vtb, uint16_t* __restrict__ ab) {
    __shared__ __align__(16) uint8_t smem[49152];   // KT[3][64][64] | VT[3][64][64]
    uint16_t* KT0 = (uint16_t*)smem;                 // + buf*4096 elems
    uint16_t* VT0 = (uint16_t*)(smem + 24576);
    float* Mlp = (float*)smem;                       // epilogue overlay (K/V dead)
    float* Llp = Mlp + 64;
    float* Ofp = Llp + 64;                           // Of[64][68] f32

    const int t = threadIdx.x;
    const int w = t >> 6, lane = t & 63;
    const int qw = w & 1, khalf = w >> 1;
    const int l31 = lane & 31, hi = lane >> 5;
    const int i8 = lane >> 3, c8 = lane & 7;
    const int id = blockIdx.x;
    const int xcd = id & 7, slot = id >> 3;
    const int lh = slot % 3, qs = slot / 3;
    const int qi = 31 - qs;                    // heavy q-blocks dispatch first
    const int bh = xcd * 3 + lh;
    const int qbase = qi * 64;
    const int q = qbase + qw * 32 + l31;
    const uint16_t* qh = qb + (size_t)bh * (SS * 64);
    const uint16_t* kh = kb + (size_t)bh * (SS * 64);
    const uint16_t* vh = vtb + (size_t)bh * (64 * SS);
    const int nkt = qi + 1;

    bf16x8 qf[4];
#pragma unroll
    for (int dc = 0; dc < 4; ++dc)
        qf[dc] = *(const bf16x8*)(qh + (size_t)q * 64 + dc * 16 + hi * 8);

    f32x16 o0, o1;
#pragma unroll
    for (int i = 0; i < 16; ++i) { o0[i] = 0.f; o1[i] = 0.f; }
    float m_run = -1e30f, l_run = 0.f;

    const uint16_t* ksrc = kh + (size_t)i8 * 64 + ((c8 ^ i8) << 3);
    const uint16_t* vsrc = vh + (size_t)i8 * SS + ((c8 ^ i8) << 3);
    const int j0 = (w & 1) * 4;

#define ASTAGE(buf, nb) do { \
    if (khalf == 0) { \
        uint16_t* KTn = KT0 + (buf) * 4096; \
        _Pragma("unroll") \
        for (int j = 0; j < 4; ++j) \
            gload16(ksrc + (size_t)((nb) + (j0 + j) * 8) * 64, KTn + (j0 + j) * 8 * 64); \
    } else { \
        uint16_t* VTn = VT0 + (buf) * 4096; \
        _Pragma("unroll") \
        for (int j = 0; j < 4; ++j) \
            gload16(vsrc + (size_t)((j0 + j) * 8) * SS + (nb), VTn + (j0 + j) * 8 * 64); \
    } \
} while (0)

    ASTAGE(0, 0);
    if (nkt > 1) ASTAGE(1, 64);

    int cur = 0;                     // buffer index = kt % 3
    for (int kt = 0; kt < nkt; ++kt) {
        if (kt + 1 < nkt) asm volatile("s_waitcnt vmcnt(4)" ::: "memory");
        else              asm volatile("s_waitcnt vmcnt(0)" ::: "memory");
        __builtin_amdgcn_s_barrier();
        __builtin_amdgcn_sched_barrier(0);
        if (kt + 2 < nkt) {
            int b2 = cur + 2; if (b2 >= 3) b2 -= 3;
            ASTAGE(b2, (kt + 2) << 6);
        }
        const uint16_t* KTc = KT0 + cur * 4096;
        const uint16_t* VTc = VT0 + cur * 4096;

        f32x16 sa;
#pragma unroll
        for (int i = 0; i < 16; ++i) sa[i] = 0.f;
        const int krow = khalf * 32 + l31;
        __builtin_amdgcn_s_setprio(1);
#pragma unroll
        for (int dc = 0; dc < 4; ++dc) {
            bf16x8 kf = *(const bf16x8*)(KTc + krow * 64 + (((dc * 2 + hi) ^ (l31 & 7)) << 3));
            sa = __builtin_amdgcn_mfma_f32_32x32x16_bf16(kf, qf[dc], sa, 0, 0, 0);
        }
        __builtin_amdgcn_s_setprio(0);
        if (kt == qi) {
            const int qrel = qw * 32 + l31;
#pragma unroll
            for (int r = 0; r < 16; ++r) {
                int key = khalf * 32 + (r & 3) + 8 * (r >> 2) + 4 * hi;
                sa[r] = (key > qrel) ? -1e30f : sa[r];
            }
        }
        float m8[8];
#pragma unroll
        for (int g = 0; g < 8; ++g) m8[g] = fmaxf(sa[g * 2], sa[g * 2 + 1]);
        float lm = fmaxf(fmaxf(fmaxf(m8[0], m8[1]), fmaxf(m8[2], m8[3])),
                         fmaxf(fmaxf(m8[4], m8[5]), fmaxf(m8[6], m8[7])));
        if (__any(lm > m_run + 8.f)) {
            float tmf = fmaxf(lm, __shfl_xor(lm, 32));
            float nm = fmaxf(m_run, tmf);
            float corr = __builtin_amdgcn_exp2f(m_run - nm);
            l_run *= corr;
#pragma unroll
            for (int i = 0; i < 16; ++i) { o0[i] *= corr; o1[i] *= corr; }
            m_run = nm;
        }
        float e[16];
#pragma unroll
        for (int r = 0; r < 16; ++r) e[r] = __builtin_amdgcn_exp2f(sa[r] - m_run);
        bf16x8 pa0, pa1;
#pragma unroll
        for (int r = 0; r < 8; ++r) { pa0[r] = (__bf16)e[r]; pa1[r] = (__bf16)e[8 + r]; }
        l_run += ((e[0] + e[1]) + (e[2] + e[3])) + ((e[4] + e[5]) + (e[6] + e[7]))
               + ((e[8] + e[9]) + (e[10] + e[11])) + ((e[12] + e[13]) + (e[14] + e[15]));
        const int rx = l31 & 7;
        __builtin_amdgcn_s_setprio(1);
#pragma unroll
        for (int dblk = 0; dblk < 2; ++dblk) {
            const uint16_t* vrow = VTc + (dblk * 32 + l31) * 64;
            ushort4 v0 = *(const ushort4*)(vrow + (((khalf * 4 + 0) ^ rx) << 3) + hi * 4);
            ushort4 v1 = *(const ushort4*)(vrow + (((khalf * 4 + 1) ^ rx) << 3) + hi * 4);
            ushort4 v2 = *(const ushort4*)(vrow + (((khalf * 4 + 2) ^ rx) << 3) + hi * 4);
            ushort4 v3 = *(const ushort4*)(vrow + (((khalf * 4 + 3) ^ rx) << 3) + hi * 4);
            f32x16 oo = dblk ? o1 : o0;
            oo = __builtin_amdgcn_mfma_f32_32x32x16_bf16(vfrag(v0, v1), pa0, oo, 0, 0, 0);
            oo = __builtin_amdgcn_mfma_f32_32x32x16_bf16(vfrag(v2, v3), pa1, oo, 0, 0, 0);
            if (dblk) o1 = oo; else o0 = oo;
        }
        __builtin_amdgcn_s_setprio(0);
        cur = (cur == 2) ? 0 : cur + 1;
    }
#undef ASTAGE

    __syncthreads();   // all waves done reading K/V LDS before overlay writes

    const float lf = l_run + __shfl_xor(l_run, 32);
    const int qrow = qw * 32 + l31;
    if (khalf == 1) {
        if (hi == 0) { Mlp[qrow] = m_run; Llp[qrow] = lf; }
#pragma unroll
        for (int dblk = 0; dblk < 2; ++dblk)
#pragma unroll
            for (int rg = 0; rg < 4; ++rg) {
                f32x16 oo = dblk ? o1 : o0;
                f32x4 v;
                v[0] = oo[rg * 4 + 0]; v[1] = oo[rg * 4 + 1];
                v[2] = oo[rg * 4 + 2]; v[3] = oo[rg * 4 + 3];
                *(f32x4*)&Ofp[qrow * 68 + dblk * 32 + rg * 8 + hi * 4] = v;
            }
    }
    __syncthreads();
    if (khalf == 0) {
        const float m2 = Mlp[qrow], l2 = Llp[qrow];
        const float ms = fmaxf(m_run, m2);
        const float wA = __builtin_amdgcn_exp2f(m_run - ms);
        const float wB = __builtin_amdgcn_exp2f(m2 - ms);
        const float inv = 1.f / (lf * wA + l2 * wB);
        const int b = bh / NHEAD, h = bh - b * NHEAD;
        uint16_t* abp = ab + ((size_t)(b * SS + q)) * NXC + h * 64;
#pragma unroll
        for (int dblk = 0; dblk < 2; ++dblk)
#pragma unroll
            for (int rg = 0; rg < 4; ++rg) {
                f32x16 oo = dblk ? o1 : o0;
                f32x4 po = *(const f32x4*)&Ofp[qrow * 68 + dblk * 32 + rg * 8 + hi * 4];
                ushort4 wv;
                wv.x = f2bf((oo[rg * 4 + 0] * wA + po[0] * wB) * inv);
                wv.y = f2bf((oo[rg * 4 + 1] * wA + po[1] * wB) * inv);
                wv.z = f2bf((oo[rg * 4 + 2] * wA + po[2] * wB) * inv);
                wv.w = f2bf((oo[rg * 4 + 3] * wA + po[3] * wB) * inv);
                *(ushort4*)(abp + dblk * 32 + rg * 8 + hi * 4) = wv;
            }
    }
}

// ---------------- launch ----------------

extern "C" void kernel_launch(void* const* d_in, const int* in_sizes, int n_in,
                              void* d_out, int out_size, void* d_ws, size_t ws_size,
                              hipStream_t stream) {
    const float* x      = (const float*)d_in[0];
    const float* w_attn = (const float*)d_in[1];
    const float* b_attn = (const float*)d_in[2];
    const float* lora_A = (const float*)d_in[3];
    const float* lora_B = (const float*)d_in[4];
    const float* w_proj = (const float*)d_in[5];
    const float* b_proj = (const float*)d_in[6];
    float* out = (float*)d_out;
    float* present = out + (size_t)MTOT * NXC;   // 3145728

    uint16_t* ws    = (uint16_t*)d_ws;
    uint16_t* x_bf  = ws;                         // 3145728
    uint16_t* weffT = x_bf + 3145728;             // 1769472
    uint16_t* wpT   = weffT + 1769472;            // 589824
    uint16_t* q_bf  = wpT + 589824;               // 3145728
    uint16_t* k_bf  = q_bf + 3145728;             // 3145728
    uint16_t* vT_bf = k_bf + 3145728;             // 3145728
    uint16_t* a_bf  = vT_bf + 3145728;            // 3145728

    prep_all<<<dim3(3648), dim3(256), 0, stream>>>(x, x_bf, w_attn, lora_A, lora_B,
                                                   weffT, w_proj, wpT);
    // gemm0: 4096x2304, 128x64 tile -> 1152 blocks (XCD-swizzled)
    gemm_bt<0, 128, 64, 36><<<dim3(1152), dim3(256), 0, stream>>>(
        x_bf, weffT, b_attn, present, q_bf, k_bf, vT_bf);
    attn_kernel<<<dim3(768), dim3(256), 0, stream>>>(q_bf, k_bf, vT_bf, a_bf);
    // gemm1: 4096x768, 64x64 tile -> 768 blocks (3/CU vs 1.5/CU at 128x64)
    gemm_bt<1, 64, 64, 12><<<dim3(768), dim3(256), 0, stream>>>(
        a_bf, wpT, b_proj, out, nullptr, nullptr, nullptr);
}